// Round 2
// baseline (975.329 us; speedup 1.0000x reference)
//
#include <hip/hip_runtime.h>
#include <hip/hip_bf16.h>
#include <stdint.h>

typedef unsigned short ushort_t;
typedef __bf16 bf16x8 __attribute__((ext_vector_type(8)));
typedef float f32x4 __attribute__((ext_vector_type(4)));

#define BM 128
#define BN 128
#define BK 32

// ---------- helpers ----------
__device__ inline float b2f(ushort_t u) {
    unsigned int x = ((unsigned int)u) << 16;
    float f; __builtin_memcpy(&f, &x, 4); return f;
}
__device__ inline ushort_t f2b(float f) {
    unsigned int x; __builtin_memcpy(&x, &f, 4);
    unsigned int r = (x + 0x7FFFu + ((x >> 16) & 1u)) >> 16;
    return (ushort_t)r;
}
__device__ inline void stage16(const ushort_t* g, ushort_t* s) {
    __builtin_amdgcn_global_load_lds((const __attribute__((address_space(1))) void*)g,
                                     (__attribute__((address_space(3))) void*)s, 16, 0, 0);
}

// ---------- fp32 -> bf16 convert ----------
__global__ void k_cvt(const float* __restrict__ in, ushort_t* __restrict__ out, int n) {
    int i = blockIdx.x * blockDim.x + threadIdx.x;
    if (i < n) out[i] = f2b(in[i]);
}

// ---------- causal depthwise conv (K=5), fp32 in, bf16 out ----------
__global__ void k_conv(const float* __restrict__ x, const float* __restrict__ w,
                       const float* __restrict__ bias, ushort_t* __restrict__ out,
                       int T, int D, int n) {
    int idx = blockIdx.x * blockDim.x + threadIdx.x;
    if (idx >= n) return;
    int d = idx % D;
    int t = (idx / D) % T;
    int b = idx / (D * T);
    float acc = bias[d];
#pragma unroll
    for (int k = 0; k < 5; ++k) {
        int ts = t - 4 + k;
        if (ts >= 0) acc += x[(long long)b * T * D + (long long)ts * D + d] * w[d * 5 + k];
    }
    out[idx] = f2b(acc);
}

// ---------- batched bf16 transpose: in (Z,R,C) -> out (Z,C,R) ----------
__global__ __launch_bounds__(256) void k_transpose(const ushort_t* __restrict__ in,
                                                   ushort_t* __restrict__ out, int R, int C) {
    __shared__ ushort_t tile[32][33];
    int z = blockIdx.z;
    int c0 = blockIdx.x * 32, r0 = blockIdx.y * 32;
    int tx = threadIdx.x & 31, ty = threadIdx.x >> 5; // 32 x 8
    const ushort_t* ip = in + (long long)z * R * C;
    ushort_t* op = out + (long long)z * R * C;
#pragma unroll
    for (int j = 0; j < 32; j += 8)
        tile[ty + j][tx] = ip[(long long)(r0 + ty + j) * C + (c0 + tx)];
    __syncthreads();
#pragma unroll
    for (int j = 0; j < 32; j += 8)
        op[(long long)(c0 + ty + j) * R + (r0 + tx)] = tile[tx][ty + j];
}

// ---------- generic bf16 NT GEMM: C[m,n] = scale * sum_k A[m,k]*B[n,k] ----------
// OM: 0 = fp32 store, 1 = bf16 store, 2 = fp32 accumulate (+=)
// KG: if true, effective K = K0*(ii+1)  (variable-K batched)
template <int OM, bool KG>
__global__ __launch_bounds__(256)
void k_gemm_nt(const ushort_t* __restrict__ A, const ushort_t* __restrict__ B,
               void* __restrict__ Cv, int K0, int lda, int ldb, int ldc,
               long long sAb, long long sAi, long long sBb, long long sBi,
               long long sCb, long long sCi, int ni, float scale) {
    __shared__ __attribute__((aligned(16))) ushort_t sA[BM * BK];
    __shared__ __attribute__((aligned(16))) ushort_t sB[BN * BK];

    const int z = blockIdx.z, bb = z / ni, ii = z % ni;
    const int K = KG ? K0 * (ii + 1) : K0;
    const int m0 = blockIdx.y * BM;
    const int n0 = blockIdx.x * BN;
    const ushort_t* Ab = A + bb * sAb + ii * sAi + (long long)m0 * lda;
    const ushort_t* Bb = B + bb * sBb + ii * sBi + (long long)n0 * ldb;

    const int tid = threadIdx.x;
    const int lane = tid & 63, quad = lane >> 4, l16 = lane & 15;
    const int wave = tid >> 6;
    const int wm = (wave >> 1) * 64, wn = (wave & 1) * 64;

    f32x4 acc[4][4];
#pragma unroll
    for (int i = 0; i < 4; ++i)
#pragma unroll
        for (int j = 0; j < 4; ++j) acc[i][j] = (f32x4){0.f, 0.f, 0.f, 0.f};

    const int e0 = tid, e1 = tid + 256;
    const int row0 = e0 >> 2, kc0 = (e0 & 3) * 8;
    const int row1 = e1 >> 2, kc1 = (e1 & 3) * 8;

    for (int k0 = 0; k0 < K; k0 += BK) {
        __syncthreads();
        stage16(Ab + (long long)row0 * lda + k0 + kc0, &sA[e0 * 8]);
        stage16(Ab + (long long)row1 * lda + k0 + kc1, &sA[e1 * 8]);
        stage16(Bb + (long long)row0 * ldb + k0 + kc0, &sB[e0 * 8]);
        stage16(Bb + (long long)row1 * ldb + k0 + kc1, &sB[e1 * 8]);
        __syncthreads();

        bf16x8 af[4], bfr[4];
#pragma unroll
        for (int mi = 0; mi < 4; ++mi)
            af[mi] = *(const bf16x8*)&sA[(wm + mi * 16 + l16) * BK + quad * 8];
#pragma unroll
        for (int nj = 0; nj < 4; ++nj)
            bfr[nj] = *(const bf16x8*)&sB[(wn + nj * 16 + l16) * BK + quad * 8];
#pragma unroll
        for (int mi = 0; mi < 4; ++mi)
#pragma unroll
            for (int nj = 0; nj < 4; ++nj)
                acc[mi][nj] = __builtin_amdgcn_mfma_f32_16x16x32_bf16(af[mi], bfr[nj], acc[mi][nj], 0, 0, 0);
    }

    const long long coff = bb * sCb + ii * sCi;
#pragma unroll
    for (int mi = 0; mi < 4; ++mi) {
        int row = m0 + wm + mi * 16 + quad * 4;
#pragma unroll
        for (int nj = 0; nj < 4; ++nj) {
            int col = n0 + wn + nj * 16 + l16;
#pragma unroll
            for (int r = 0; r < 4; ++r) {
                long long o = coff + (long long)(row + r) * ldc + col;
                if constexpr (OM == 1) ((ushort_t*)Cv)[o] = f2b(acc[mi][nj][r] * scale);
                else if constexpr (OM == 0) ((float*)Cv)[o] = acc[mi][nj][r] * scale;
                else ((float*)Cv)[o] += acc[mi][nj][r] * scale;
            }
        }
    }
}

// ---------- fused gate_up GEMM + SiLU epilogue: h = silu(x@Wg^T) * (x@Wu^T) ----------
__global__ __launch_bounds__(256)
void k_gemm_silu(const ushort_t* __restrict__ A, const ushort_t* __restrict__ Bg,
                 const ushort_t* __restrict__ Bu, ushort_t* __restrict__ H,
                 int K, int lda, int ldb, int ldh) {
    __shared__ __attribute__((aligned(16))) ushort_t sA[BM * BK];
    __shared__ __attribute__((aligned(16))) ushort_t sBg[BN * BK];
    __shared__ __attribute__((aligned(16))) ushort_t sBu[BN * BK];

    const int m0 = blockIdx.y * BM;
    const int n0 = blockIdx.x * BN;
    const ushort_t* Ab = A + (long long)m0 * lda;
    const ushort_t* Bgb = Bg + (long long)n0 * ldb;
    const ushort_t* Bub = Bu + (long long)n0 * ldb;

    const int tid = threadIdx.x;
    const int lane = tid & 63, quad = lane >> 4, l16 = lane & 15;
    const int wave = tid >> 6;
    const int wm = (wave >> 1) * 64, wn = (wave & 1) * 64;

    f32x4 ag[4][4], au[4][4];
#pragma unroll
    for (int i = 0; i < 4; ++i)
#pragma unroll
        for (int j = 0; j < 4; ++j) { ag[i][j] = (f32x4){0,0,0,0}; au[i][j] = (f32x4){0,0,0,0}; }

    const int e0 = tid, e1 = tid + 256;
    const int row0 = e0 >> 2, kc0 = (e0 & 3) * 8;
    const int row1 = e1 >> 2, kc1 = (e1 & 3) * 8;

    for (int k0 = 0; k0 < K; k0 += BK) {
        __syncthreads();
        stage16(Ab  + (long long)row0 * lda + k0 + kc0, &sA[e0 * 8]);
        stage16(Ab  + (long long)row1 * lda + k0 + kc1, &sA[e1 * 8]);
        stage16(Bgb + (long long)row0 * ldb + k0 + kc0, &sBg[e0 * 8]);
        stage16(Bgb + (long long)row1 * ldb + k0 + kc1, &sBg[e1 * 8]);
        stage16(Bub + (long long)row0 * ldb + k0 + kc0, &sBu[e0 * 8]);
        stage16(Bub + (long long)row1 * ldb + k0 + kc1, &sBu[e1 * 8]);
        __syncthreads();

        bf16x8 af[4], bg[4], bu[4];
#pragma unroll
        for (int mi = 0; mi < 4; ++mi)
            af[mi] = *(const bf16x8*)&sA[(wm + mi * 16 + l16) * BK + quad * 8];
#pragma unroll
        for (int nj = 0; nj < 4; ++nj) {
            bg[nj] = *(const bf16x8*)&sBg[(wn + nj * 16 + l16) * BK + quad * 8];
            bu[nj] = *(const bf16x8*)&sBu[(wn + nj * 16 + l16) * BK + quad * 8];
        }
#pragma unroll
        for (int mi = 0; mi < 4; ++mi)
#pragma unroll
            for (int nj = 0; nj < 4; ++nj) {
                ag[mi][nj] = __builtin_amdgcn_mfma_f32_16x16x32_bf16(af[mi], bg[nj], ag[mi][nj], 0, 0, 0);
                au[mi][nj] = __builtin_amdgcn_mfma_f32_16x16x32_bf16(af[mi], bu[nj], au[mi][nj], 0, 0, 0);
            }
    }

#pragma unroll
    for (int mi = 0; mi < 4; ++mi) {
        int row = m0 + wm + mi * 16 + quad * 4;
#pragma unroll
        for (int nj = 0; nj < 4; ++nj) {
            int col = n0 + wn + nj * 16 + l16;
#pragma unroll
            for (int r = 0; r < 4; ++r) {
                float g = ag[mi][nj][r], u = au[mi][nj][r];
                float s = g / (1.f + __expf(-g));
                H[(long long)(row + r) * ldh + col] = f2b(s * u);
            }
        }
    }
}

// ---------- triangular P GEMM: P[b, i*256+m, j*256+n] = sum_f h_i[m,f] h_j[n,f], j<i ----------
__global__ __launch_bounds__(256)
void k_gemm_tri(const ushort_t* __restrict__ H, ushort_t* __restrict__ P,
                int K, int ldh, int ldp, long long sHb, long long sPb, int npairs) {
    __shared__ __attribute__((aligned(16))) ushort_t sA[BM * BK];
    __shared__ __attribute__((aligned(16))) ushort_t sB[BN * BK];

    const int z = blockIdx.z, bb = z / npairs;
    int p = z % npairs;
    int i = 1, rem = p;
    while (rem >= i) { rem -= i; ++i; }
    const int j = rem;

    const int m0 = blockIdx.y * BM;
    const int n0 = blockIdx.x * BN;
    const ushort_t* Ab = H + bb * sHb + (long long)(i * 256 + m0) * ldh;
    const ushort_t* Bb = H + bb * sHb + (long long)(j * 256 + n0) * ldh;

    const int tid = threadIdx.x;
    const int lane = tid & 63, quad = lane >> 4, l16 = lane & 15;
    const int wave = tid >> 6;
    const int wm = (wave >> 1) * 64, wn = (wave & 1) * 64;

    f32x4 acc[4][4];
#pragma unroll
    for (int a = 0; a < 4; ++a)
#pragma unroll
        for (int c = 0; c < 4; ++c) acc[a][c] = (f32x4){0,0,0,0};

    const int e0 = tid, e1 = tid + 256;
    const int row0 = e0 >> 2, kc0 = (e0 & 3) * 8;
    const int row1 = e1 >> 2, kc1 = (e1 & 3) * 8;

    for (int k0 = 0; k0 < K; k0 += BK) {
        __syncthreads();
        stage16(Ab + (long long)row0 * ldh + k0 + kc0, &sA[e0 * 8]);
        stage16(Ab + (long long)row1 * ldh + k0 + kc1, &sA[e1 * 8]);
        stage16(Bb + (long long)row0 * ldh + k0 + kc0, &sB[e0 * 8]);
        stage16(Bb + (long long)row1 * ldh + k0 + kc1, &sB[e1 * 8]);
        __syncthreads();

        bf16x8 af[4], bfr[4];
#pragma unroll
        for (int mi = 0; mi < 4; ++mi)
            af[mi] = *(const bf16x8*)&sA[(wm + mi * 16 + l16) * BK + quad * 8];
#pragma unroll
        for (int nj = 0; nj < 4; ++nj)
            bfr[nj] = *(const bf16x8*)&sB[(wn + nj * 16 + l16) * BK + quad * 8];
#pragma unroll
        for (int mi = 0; mi < 4; ++mi)
#pragma unroll
            for (int nj = 0; nj < 4; ++nj)
                acc[mi][nj] = __builtin_amdgcn_mfma_f32_16x16x32_bf16(af[mi], bfr[nj], acc[mi][nj], 0, 0, 0);
    }

    ushort_t* Pp = P + bb * sPb;
#pragma unroll
    for (int mi = 0; mi < 4; ++mi) {
        int row = i * 256 + m0 + wm + mi * 16 + quad * 4;
#pragma unroll
        for (int nj = 0; nj < 4; ++nj) {
            int col = j * 256 + n0 + wn + nj * 16 + l16;
#pragma unroll
            for (int r = 0; r < 4; ++r)
                Pp[(long long)(row + r) * ldp + col] = f2b(acc[mi][nj][r]);
        }
    }
}

// ---------- launch ----------
extern "C" void kernel_launch(void* const* d_in, const int* in_sizes, int n_in,
                              void* d_out, int out_size, void* d_ws, size_t ws_size,
                              hipStream_t stream) {
    const float* x         = (const float*)d_in[0];
    const float* ttt_tgt   = (const float*)d_in[1];
    const float* w_gate_up = (const float*)d_in[2];
    const float* w_down    = (const float*)d_in[3];
    const float* ttt_proj  = (const float*)d_in[4];
    const float* conv_w    = (const float*)d_in[5];
    const float* conv_b    = (const float*)d_in[6];
    float* out = (float*)d_out;
    (void)in_sizes; (void)n_in; (void)out_size; (void)ws_size;

    constexpr int Bb = 2, T = 4096, D = 1024, F = 4096, C = 256;
    constexpr float LR = 0.01f;

    // workspace layout (161.5 MB total):
    //   [0,16M)   x_bf    \
    //   [16,32M)  wgu_bf   |  these 4 (67.1 MB) are later aliased by P (B,T,T) bf16
    //   [32,48M)  t_bf     |  (all dead before P is written)
    //   [48,64M)  tproj   /
    //   [64M..)   proj_bf 2M | wdown_bf 8M | tpT 16M | h 64M
    char* ws = (char*)d_ws;
    ushort_t* x_bf     = (ushort_t*)(ws);
    ushort_t* wgu_bf   = (ushort_t*)(ws + 16777216LL);
    ushort_t* t_bf     = (ushort_t*)(ws + 2 * 16777216LL);
    ushort_t* tproj    = (ushort_t*)(ws + 3 * 16777216LL);
    ushort_t* P        = (ushort_t*)(ws);                       // alias, 67108864 B
    ushort_t* proj_bf  = (ushort_t*)(ws + 67108864LL);
    ushort_t* wdown_bf = (ushort_t*)(ws + 67108864LL + 2097152LL);
    ushort_t* tpT      = (ushort_t*)(ws + 67108864LL + 2097152LL + 8388608LL);
    ushort_t* h        = (ushort_t*)(ws + 67108864LL + 2097152LL + 8388608LL + 16777216LL);

    // 1) converts
    k_cvt<<<(Bb * T * D) / 256, 256, 0, stream>>>(x, x_bf, Bb * T * D);
    k_cvt<<<(2 * F * D) / 256, 256, 0, stream>>>(w_gate_up, wgu_bf, 2 * F * D);
    k_cvt<<<(D * D) / 256, 256, 0, stream>>>(ttt_proj, proj_bf, D * D);
    k_cvt<<<(D * F) / 256, 256, 0, stream>>>(w_down, wdown_bf, D * F);

    // 2) causal depthwise conv -> t_bf (B,T,D) bf16
    k_conv<<<(Bb * T * D) / 256, 256, 0, stream>>>(ttt_tgt, conv_w, conv_b, t_bf, T, D, Bb * T * D);

    // 3) tproj = t @ ttt_proj^T : M=B*T, N=D, K=D -> bf16
    k_gemm_nt<1, false><<<dim3(D / BN, (Bb * T) / BM, 1), 256, 0, stream>>>(
        t_bf, proj_bf, tproj, D, D, D, D, 0, 0, 0, 0, 0, 0, 1, 1.f);

    // 4) transpose per batch: tproj (B,T,D) -> tpT (B,D,T)
    k_transpose<<<dim3(D / 32, T / 32, Bb), 256, 0, stream>>>(tproj, tpT, T, D);

    // 5) h = silu(x@Wg^T)*(x@Wu^T) : M=B*T, N=F, K=D  (fused dual GEMM)
    k_gemm_silu<<<dim3(F / BN, (Bb * T) / BM, 1), 256, 0, stream>>>(
        x_bf, wgu_bf, wgu_bf + (long long)F * D, h, D, D, D, F);

    // 6) out = h @ w_down^T : M=B*T, N=D, K=F -> fp32 d_out (covers every element)
    k_gemm_nt<0, false><<<dim3(D / BN, (Bb * T) / BM, 1), 256, 0, stream>>>(
        h, wdown_bf, out, F, F, F, D, 0, 0, 0, 0, 0, 0, 1, 1.f);

    // 7) P lower chunk-blocks: P[b, i*C.., j*C..] = h_i h_j^T, j<i  (120 pairs/batch)
    k_gemm_tri<<<dim3(C / BN, C / BM, Bb * 120), 256, 0, stream>>>(
        h, P, F, F, T, (long long)T * F, (long long)T * T, 120);

    // 8) out[b, i*C..] += LR * P[b, i*C.., 0:i*C] @ tpT[b]^T  (variable K = i*C)
    k_gemm_nt<2, true><<<dim3(D / BN, C / BM, Bb * 15), 256, 0, stream>>>(
        P + (long long)C * T, tpT, out + (long long)C * D,
        C, T, T, D,
        (long long)T * T, (long long)C * T,
        (long long)D * T, 0,
        (long long)T * D, (long long)C * D,
        15, LR);
}

// Round 3
// 819.302 us; speedup vs baseline: 1.1904x; 1.1904x over previous
//
#include <hip/hip_runtime.h>
#include <hip/hip_bf16.h>
#include <stdint.h>

typedef unsigned short ushort_t;
typedef __bf16 bf16x8 __attribute__((ext_vector_type(8)));
typedef float f32x4 __attribute__((ext_vector_type(4)));

#define BM 128
#define BN 128
#define BK 64   // 16 KB per tile; XOR-swizzled 16B chunks (bank-conflict-free)

// ---------- helpers ----------
__device__ inline float b2f(ushort_t u) {
    unsigned int x = ((unsigned int)u) << 16;
    float f; __builtin_memcpy(&f, &x, 4); return f;
}
__device__ inline ushort_t f2b(float f) {
    unsigned int x; __builtin_memcpy(&x, &f, 4);
    unsigned int r = (x + 0x7FFFu + ((x >> 16) & 1u)) >> 16;
    return (ushort_t)r;
}
__device__ inline void stage16(const ushort_t* g, ushort_t* s) {
    __builtin_amdgcn_global_load_lds((const __attribute__((address_space(1))) void*)g,
                                     (__attribute__((address_space(3))) void*)s, 16, 0, 0);
}
// stage one 128x64 bf16 tile; LDS chunk e holds global chunk ((e&7)^(row&7)) of row e>>3
__device__ inline void stage_tile(const ushort_t* G, int ld, int k0, ushort_t* S, int tid) {
#pragma unroll
    for (int t = 0; t < 4; ++t) {
        int e = tid + t * 256;
        int row = e >> 3;
        int sw = ((e & 7) ^ (row & 7)) * 8;
        stage16(G + (long long)row * ld + k0 + sw, &S[e * 8]);
    }
}
// read logical (row r, 16B-chunk c) fragment from swizzled tile
__device__ inline bf16x8 ldfrag(const ushort_t* S, int r, int c) {
    return *(const bf16x8*)&S[r * BK + ((c ^ (r & 7)) * 8)];
}
// grouped tile swizzle for L2 locality: G m-tiles per group, n iterated outer
__device__ inline void tile_decode(int& m0, int& n0) {
    const int nx = gridDim.x, ny = gridDim.y;
    int lin = blockIdx.y * nx + blockIdx.x;
    const int G = 8;
    int gs = G * nx;
    int g0 = (lin / gs) * G;
    int rem = lin % gs;
    int gsz = ny - g0 < G ? ny - g0 : G;
    m0 = (g0 + rem % gsz) * BM;
    n0 = (rem / gsz) * BN;
}

// ---------- fp32 -> bf16 convert ----------
__global__ void k_cvt(const float* __restrict__ in, ushort_t* __restrict__ out, int n) {
    int i = blockIdx.x * blockDim.x + threadIdx.x;
    if (i < n) out[i] = f2b(in[i]);
}

// ---------- causal depthwise conv (K=5), fp32 in, bf16 out ----------
__global__ void k_conv(const float* __restrict__ x, const float* __restrict__ w,
                       const float* __restrict__ bias, ushort_t* __restrict__ out,
                       int T, int D, int n) {
    int idx = blockIdx.x * blockDim.x + threadIdx.x;
    if (idx >= n) return;
    int d = idx % D;
    int t = (idx / D) % T;
    int b = idx / (D * T);
    float acc = bias[d];
#pragma unroll
    for (int k = 0; k < 5; ++k) {
        int ts = t - 4 + k;
        if (ts >= 0) acc += x[(long long)b * T * D + (long long)ts * D + d] * w[d * 5 + k];
    }
    out[idx] = f2b(acc);
}

// ---------- batched bf16 transpose: in (Z,R,C) -> out (Z,C,R) ----------
__global__ __launch_bounds__(256) void k_transpose(const ushort_t* __restrict__ in,
                                                   ushort_t* __restrict__ out, int R, int C) {
    __shared__ ushort_t tile[32][33];
    int z = blockIdx.z;
    int c0 = blockIdx.x * 32, r0 = blockIdx.y * 32;
    int tx = threadIdx.x & 31, ty = threadIdx.x >> 5;
    const ushort_t* ip = in + (long long)z * R * C;
    ushort_t* op = out + (long long)z * R * C;
#pragma unroll
    for (int j = 0; j < 32; j += 8)
        tile[ty + j][tx] = ip[(long long)(r0 + ty + j) * C + (c0 + tx)];
    __syncthreads();
#pragma unroll
    for (int j = 0; j < 32; j += 8)
        op[(long long)(c0 + ty + j) * R + (r0 + tx)] = tile[tx][ty + j];
}

// ---------- generic bf16 NT GEMM: C[m,n] = scale * sum_k A[m,k]*B[n,k] ----------
// OM: 0 = fp32 store, 1 = bf16 store, 2 = fp32 accumulate (+=)
// KG: if true, effective K = K0*(ii+1)
template <int OM, bool KG>
__global__ __launch_bounds__(256)
void k_gemm_nt(const ushort_t* __restrict__ A, const ushort_t* __restrict__ B,
               void* __restrict__ Cv, int K0, int lda, int ldb, int ldc,
               long long sAb, long long sAi, long long sBb, long long sBi,
               long long sCb, long long sCi, int ni, float scale) {
    __shared__ __attribute__((aligned(16))) ushort_t sA[BM * BK];
    __shared__ __attribute__((aligned(16))) ushort_t sB[BN * BK];

    const int z = blockIdx.z, bb = z / ni, ii = z % ni;
    const int K = KG ? K0 * (ii + 1) : K0;
    int m0, n0;
    tile_decode(m0, n0);
    const ushort_t* Ab = A + bb * sAb + ii * sAi + (long long)m0 * lda;
    const ushort_t* Bb = B + bb * sBb + ii * sBi + (long long)n0 * ldb;

    const int tid = threadIdx.x;
    const int lane = tid & 63, quad = lane >> 4, l16 = lane & 15;
    const int wave = tid >> 6;
    const int wm = (wave >> 1) * 64, wn = (wave & 1) * 64;

    f32x4 acc[4][4];
#pragma unroll
    for (int i = 0; i < 4; ++i)
#pragma unroll
        for (int j = 0; j < 4; ++j) acc[i][j] = (f32x4){0.f, 0.f, 0.f, 0.f};

    for (int k0 = 0; k0 < K; k0 += BK) {
        __syncthreads();
        stage_tile(Ab, lda, k0, sA, tid);
        stage_tile(Bb, ldb, k0, sB, tid);
        __syncthreads();
#pragma unroll
        for (int kh = 0; kh < 2; ++kh) {
            bf16x8 af[4], bfr[4];
#pragma unroll
            for (int mi = 0; mi < 4; ++mi)
                af[mi] = ldfrag(sA, wm + mi * 16 + l16, kh * 4 + quad);
#pragma unroll
            for (int nj = 0; nj < 4; ++nj)
                bfr[nj] = ldfrag(sB, wn + nj * 16 + l16, kh * 4 + quad);
#pragma unroll
            for (int mi = 0; mi < 4; ++mi)
#pragma unroll
                for (int nj = 0; nj < 4; ++nj)
                    acc[mi][nj] = __builtin_amdgcn_mfma_f32_16x16x32_bf16(af[mi], bfr[nj], acc[mi][nj], 0, 0, 0);
        }
    }

    const long long coff = bb * sCb + ii * sCi;
#pragma unroll
    for (int mi = 0; mi < 4; ++mi) {
        int row = m0 + wm + mi * 16 + quad * 4;
#pragma unroll
        for (int nj = 0; nj < 4; ++nj) {
            int col = n0 + wn + nj * 16 + l16;
#pragma unroll
            for (int r = 0; r < 4; ++r) {
                long long o = coff + (long long)(row + r) * ldc + col;
                if constexpr (OM == 1) ((ushort_t*)Cv)[o] = f2b(acc[mi][nj][r] * scale);
                else if constexpr (OM == 0) ((float*)Cv)[o] = acc[mi][nj][r] * scale;
                else ((float*)Cv)[o] += acc[mi][nj][r] * scale;
            }
        }
    }
}

// ---------- fused gate_up GEMM + SiLU: h = silu(x@Wg^T) * (x@Wu^T) ----------
__global__ __launch_bounds__(256)
void k_gemm_silu(const ushort_t* __restrict__ A, const ushort_t* __restrict__ Bg,
                 const ushort_t* __restrict__ Bu, ushort_t* __restrict__ H,
                 int K, int lda, int ldb, int ldh) {
    __shared__ __attribute__((aligned(16))) ushort_t sA[BM * BK];
    __shared__ __attribute__((aligned(16))) ushort_t sBg[BN * BK];
    __shared__ __attribute__((aligned(16))) ushort_t sBu[BN * BK];

    int m0, n0;
    tile_decode(m0, n0);
    const ushort_t* Ab = A + (long long)m0 * lda;
    const ushort_t* Bgb = Bg + (long long)n0 * ldb;
    const ushort_t* Bub = Bu + (long long)n0 * ldb;

    const int tid = threadIdx.x;
    const int lane = tid & 63, quad = lane >> 4, l16 = lane & 15;
    const int wave = tid >> 6;
    const int wm = (wave >> 1) * 64, wn = (wave & 1) * 64;

    f32x4 ag[4][4], au[4][4];
#pragma unroll
    for (int i = 0; i < 4; ++i)
#pragma unroll
        for (int j = 0; j < 4; ++j) { ag[i][j] = (f32x4){0,0,0,0}; au[i][j] = (f32x4){0,0,0,0}; }

    for (int k0 = 0; k0 < K; k0 += BK) {
        __syncthreads();
        stage_tile(Ab, lda, k0, sA, tid);
        stage_tile(Bgb, ldb, k0, sBg, tid);
        stage_tile(Bub, ldb, k0, sBu, tid);
        __syncthreads();
#pragma unroll
        for (int kh = 0; kh < 2; ++kh) {
            bf16x8 af[4], bg[4], bu[4];
#pragma unroll
            for (int mi = 0; mi < 4; ++mi)
                af[mi] = ldfrag(sA, wm + mi * 16 + l16, kh * 4 + quad);
#pragma unroll
            for (int nj = 0; nj < 4; ++nj) {
                bg[nj] = ldfrag(sBg, wn + nj * 16 + l16, kh * 4 + quad);
                bu[nj] = ldfrag(sBu, wn + nj * 16 + l16, kh * 4 + quad);
            }
#pragma unroll
            for (int mi = 0; mi < 4; ++mi)
#pragma unroll
                for (int nj = 0; nj < 4; ++nj) {
                    ag[mi][nj] = __builtin_amdgcn_mfma_f32_16x16x32_bf16(af[mi], bg[nj], ag[mi][nj], 0, 0, 0);
                    au[mi][nj] = __builtin_amdgcn_mfma_f32_16x16x32_bf16(af[mi], bu[nj], au[mi][nj], 0, 0, 0);
                }
        }
    }

#pragma unroll
    for (int mi = 0; mi < 4; ++mi) {
        int row = m0 + wm + mi * 16 + quad * 4;
#pragma unroll
        for (int nj = 0; nj < 4; ++nj) {
            int col = n0 + wn + nj * 16 + l16;
#pragma unroll
            for (int r = 0; r < 4; ++r) {
                float g = ag[mi][nj][r], u = au[mi][nj][r];
                float s = g / (1.f + __expf(-g));
                H[(long long)(row + r) * ldh + col] = f2b(s * u);
            }
        }
    }
}

// ---------- triangular P GEMM: P[b, i*256+m, j*256+n] = sum_f h_i[m,f] h_j[n,f], j<i ----------
__global__ __launch_bounds__(256)
void k_gemm_tri(const ushort_t* __restrict__ H, ushort_t* __restrict__ P,
                int K, int ldh, int ldp, long long sHb, long long sPb, int npairs) {
    __shared__ __attribute__((aligned(16))) ushort_t sA[BM * BK];
    __shared__ __attribute__((aligned(16))) ushort_t sB[BN * BK];

    const int z = blockIdx.z, bb = z / npairs;
    int p = z % npairs;
    int i = 1, rem = p;
    while (rem >= i) { rem -= i; ++i; }
    const int j = rem;

    const int m0 = blockIdx.y * BM;
    const int n0 = blockIdx.x * BN;
    const ushort_t* Ab = H + bb * sHb + (long long)(i * 256 + m0) * ldh;
    const ushort_t* Bb = H + bb * sHb + (long long)(j * 256 + n0) * ldh;

    const int tid = threadIdx.x;
    const int lane = tid & 63, quad = lane >> 4, l16 = lane & 15;
    const int wave = tid >> 6;
    const int wm = (wave >> 1) * 64, wn = (wave & 1) * 64;

    f32x4 acc[4][4];
#pragma unroll
    for (int a = 0; a < 4; ++a)
#pragma unroll
        for (int c = 0; c < 4; ++c) acc[a][c] = (f32x4){0,0,0,0};

    for (int k0 = 0; k0 < K; k0 += BK) {
        __syncthreads();
        stage_tile(Ab, ldh, k0, sA, tid);
        stage_tile(Bb, ldh, k0, sB, tid);
        __syncthreads();
#pragma unroll
        for (int kh = 0; kh < 2; ++kh) {
            bf16x8 af[4], bfr[4];
#pragma unroll
            for (int mi = 0; mi < 4; ++mi)
                af[mi] = ldfrag(sA, wm + mi * 16 + l16, kh * 4 + quad);
#pragma unroll
            for (int nj = 0; nj < 4; ++nj)
                bfr[nj] = ldfrag(sB, wn + nj * 16 + l16, kh * 4 + quad);
#pragma unroll
            for (int mi = 0; mi < 4; ++mi)
#pragma unroll
                for (int nj = 0; nj < 4; ++nj)
                    acc[mi][nj] = __builtin_amdgcn_mfma_f32_16x16x32_bf16(af[mi], bfr[nj], acc[mi][nj], 0, 0, 0);
        }
    }

    ushort_t* Pp = P + bb * sPb;
#pragma unroll
    for (int mi = 0; mi < 4; ++mi) {
        int row = i * 256 + m0 + wm + mi * 16 + quad * 4;
#pragma unroll
        for (int nj = 0; nj < 4; ++nj) {
            int col = j * 256 + n0 + wn + nj * 16 + l16;
#pragma unroll
            for (int r = 0; r < 4; ++r)
                Pp[(long long)(row + r) * ldp + col] = f2b(acc[mi][nj][r]);
        }
    }
}

// ---------- launch ----------
extern "C" void kernel_launch(void* const* d_in, const int* in_sizes, int n_in,
                              void* d_out, int out_size, void* d_ws, size_t ws_size,
                              hipStream_t stream) {
    const float* x         = (const float*)d_in[0];
    const float* ttt_tgt   = (const float*)d_in[1];
    const float* w_gate_up = (const float*)d_in[2];
    const float* w_down    = (const float*)d_in[3];
    const float* ttt_proj  = (const float*)d_in[4];
    const float* conv_w    = (const float*)d_in[5];
    const float* conv_b    = (const float*)d_in[6];
    float* out = (float*)d_out;
    (void)in_sizes; (void)n_in; (void)out_size; (void)ws_size;

    constexpr int Bb = 2, T = 4096, D = 1024, F = 4096, C = 256;
    constexpr float LR = 0.01f;

    // workspace (161.5 MB):
    //   [0,64M): x_bf|wgu_bf|t_bf|tproj  -> later aliased by P (B,T,T) bf16
    //   [64M..): proj_bf 2M | wdown_bf 8M | tpT 16M | h 64M
    char* ws = (char*)d_ws;
    ushort_t* x_bf     = (ushort_t*)(ws);
    ushort_t* wgu_bf   = (ushort_t*)(ws + 16777216LL);
    ushort_t* t_bf     = (ushort_t*)(ws + 2 * 16777216LL);
    ushort_t* tproj    = (ushort_t*)(ws + 3 * 16777216LL);
    ushort_t* P        = (ushort_t*)(ws);
    ushort_t* proj_bf  = (ushort_t*)(ws + 67108864LL);
    ushort_t* wdown_bf = (ushort_t*)(ws + 67108864LL + 2097152LL);
    ushort_t* tpT      = (ushort_t*)(ws + 67108864LL + 2097152LL + 8388608LL);
    ushort_t* h        = (ushort_t*)(ws + 67108864LL + 2097152LL + 8388608LL + 16777216LL);

    // 1) converts
    k_cvt<<<(Bb * T * D) / 256, 256, 0, stream>>>(x, x_bf, Bb * T * D);
    k_cvt<<<(2 * F * D) / 256, 256, 0, stream>>>(w_gate_up, wgu_bf, 2 * F * D);
    k_cvt<<<(D * D) / 256, 256, 0, stream>>>(ttt_proj, proj_bf, D * D);
    k_cvt<<<(D * F) / 256, 256, 0, stream>>>(w_down, wdown_bf, D * F);

    // 2) causal depthwise conv -> t_bf (B,T,D) bf16
    k_conv<<<(Bb * T * D) / 256, 256, 0, stream>>>(ttt_tgt, conv_w, conv_b, t_bf, T, D, Bb * T * D);

    // 3) tproj = t @ ttt_proj^T : M=B*T, N=D, K=D -> bf16
    k_gemm_nt<1, false><<<dim3(D / BN, (Bb * T) / BM, 1), 256, 0, stream>>>(
        t_bf, proj_bf, tproj, D, D, D, D, 0, 0, 0, 0, 0, 0, 1, 1.f);

    // 4) transpose per batch: tproj (B,T,D) -> tpT (B,D,T)
    k_transpose<<<dim3(D / 32, T / 32, Bb), 256, 0, stream>>>(tproj, tpT, T, D);

    // 5) h = silu(x@Wg^T)*(x@Wu^T) : M=B*T, N=F, K=D
    k_gemm_silu<<<dim3(F / BN, (Bb * T) / BM, 1), 256, 0, stream>>>(
        x_bf, wgu_bf, wgu_bf + (long long)F * D, h, D, D, D, F);

    // 6) out = h @ w_down^T : M=B*T, N=D, K=F -> fp32 d_out
    k_gemm_nt<0, false><<<dim3(D / BN, (Bb * T) / BM, 1), 256, 0, stream>>>(
        h, wdown_bf, out, F, F, F, D, 0, 0, 0, 0, 0, 0, 1, 1.f);

    // 7) P lower chunk-blocks: P[b, i*C.., j*C..] = h_i h_j^T, j<i
    k_gemm_tri<<<dim3(C / BN, C / BM, Bb * 120), 256, 0, stream>>>(
        h, P, F, F, T, (long long)T * F, (long long)T * T, 120);

    // 8) out[b, i*C..] += LR * P[b, i*C.., 0:i*C] @ tpT[b]^T  (variable K = i*C)
    k_gemm_nt<2, true><<<dim3(D / BN, C / BM, Bb * 15), 256, 0, stream>>>(
        P + (long long)C * T, tpT, out + (long long)C * D,
        C, T, T, D,
        (long long)T * T, (long long)C * T,
        (long long)D * T, 0,
        (long long)T * D, (long long)C * D,
        15, LR);
}

// Round 4
// 783.349 us; speedup vs baseline: 1.2451x; 1.0459x over previous
//
#include <hip/hip_runtime.h>
#include <hip/hip_bf16.h>
#include <stdint.h>

typedef unsigned short ushort_t;
typedef __bf16 bf16x8 __attribute__((ext_vector_type(8)));
typedef float f32x4 __attribute__((ext_vector_type(4)));

#define BM 128
#define BN 128
#define BK 64   // 16 KB per tile; XOR-swizzled 16B chunks (bank-conflict-free, verified R3)

// ---------- helpers ----------
__device__ inline float b2f(ushort_t u) {
    unsigned int x = ((unsigned int)u) << 16;
    float f; __builtin_memcpy(&f, &x, 4); return f;
}
__device__ inline ushort_t f2b(float f) {
    unsigned int x; __builtin_memcpy(&x, &f, 4);
    unsigned int r = (x + 0x7FFFu + ((x >> 16) & 1u)) >> 16;
    return (ushort_t)r;
}
__device__ inline void stage16(const ushort_t* g, ushort_t* s) {
    __builtin_amdgcn_global_load_lds((const __attribute__((address_space(1))) void*)g,
                                     (__attribute__((address_space(3))) void*)s, 16, 0, 0);
}
// stage one 128x64 bf16 tile; LDS chunk e holds global chunk ((e&7)^(row&7)) of row e>>3
__device__ inline void stage_tile(const ushort_t* G, int ld, int k0, ushort_t* S, int tid) {
#pragma unroll
    for (int t = 0; t < 4; ++t) {
        int e = tid + t * 256;
        int row = e >> 3;
        int sw = ((e & 7) ^ (row & 7)) * 8;
        stage16(G + (long long)row * ld + k0 + sw, &S[e * 8]);
    }
}
__device__ inline bf16x8 ldfrag(const ushort_t* S, int r, int c) {
    return *(const bf16x8*)&S[r * BK + ((c ^ (r & 7)) * 8)];
}
// XCD-aware tile decode: XCD = linear_block_id % 8 (round-robin). Give XCD k a
// FIXED set of nx/8 n-tiles (L2-persistent B), sweep m, cycling owned n-tiles
// every q blocks so the A m-tile also gets immediate reuse. Requires nx % 8 == 0.
__device__ inline void tile_decode(int& m0, int& n0) {
    const int nx = gridDim.x;
    int lin = blockIdx.y * nx + blockIdx.x;
    if ((nx & 7) == 0) {
        int q = nx >> 3;
        int k = lin & 7, s = lin >> 3;
        n0 = (k * q + s % q) * BN;
        m0 = (s / q) * BM;
    } else {
        m0 = blockIdx.y * BM;
        n0 = blockIdx.x * BN;
    }
}

// ---------- fp32 -> bf16 convert ----------
__global__ void k_cvt(const float* __restrict__ in, ushort_t* __restrict__ out, int n) {
    int i = blockIdx.x * blockDim.x + threadIdx.x;
    if (i < n) out[i] = f2b(in[i]);
}

// ---------- causal depthwise conv (K=5), fp32 in, bf16 out ----------
__global__ void k_conv(const float* __restrict__ x, const float* __restrict__ w,
                       const float* __restrict__ bias, ushort_t* __restrict__ out,
                       int T, int D, int n) {
    int idx = blockIdx.x * blockDim.x + threadIdx.x;
    if (idx >= n) return;
    int d = idx % D;
    int t = (idx / D) % T;
    int b = idx / (D * T);
    float acc = bias[d];
#pragma unroll
    for (int k = 0; k < 5; ++k) {
        int ts = t - 4 + k;
        if (ts >= 0) acc += x[(long long)b * T * D + (long long)ts * D + d] * w[d * 5 + k];
    }
    out[idx] = f2b(acc);
}

// ---------- batched bf16 transpose: in (Z,R,C) -> out (Z,C,R) ----------
__global__ __launch_bounds__(256) void k_transpose(const ushort_t* __restrict__ in,
                                                   ushort_t* __restrict__ out, int R, int C) {
    __shared__ ushort_t tile[32][33];
    int z = blockIdx.z;
    int c0 = blockIdx.x * 32, r0 = blockIdx.y * 32;
    int tx = threadIdx.x & 31, ty = threadIdx.x >> 5;
    const ushort_t* ip = in + (long long)z * R * C;
    ushort_t* op = out + (long long)z * R * C;
#pragma unroll
    for (int j = 0; j < 32; j += 8)
        tile[ty + j][tx] = ip[(long long)(r0 + ty + j) * C + (c0 + tx)];
    __syncthreads();
#pragma unroll
    for (int j = 0; j < 32; j += 8)
        op[(long long)(c0 + ty + j) * R + (r0 + tx)] = tile[tx][ty + j];
}

// ---------- plain bf16 NT GEMM (bf16 out): C[m,n] = scale * sum_k A[m,k]*B[n,k] ----------
__global__ __launch_bounds__(256)
void k_gemm_nt(const ushort_t* __restrict__ A, const ushort_t* __restrict__ B,
               ushort_t* __restrict__ C, int K, int lda, int ldb, int ldc, float scale) {
    __shared__ __attribute__((aligned(16))) ushort_t sA[BM * BK];
    __shared__ __attribute__((aligned(16))) ushort_t sB[BN * BK];

    int m0, n0;
    tile_decode(m0, n0);
    const ushort_t* Ab = A + (long long)m0 * lda;
    const ushort_t* Bb = B + (long long)n0 * ldb;

    const int tid = threadIdx.x;
    const int lane = tid & 63, quad = lane >> 4, l16 = lane & 15;
    const int wave = tid >> 6;
    const int wm = (wave >> 1) * 64, wn = (wave & 1) * 64;

    f32x4 acc[4][4];
#pragma unroll
    for (int i = 0; i < 4; ++i)
#pragma unroll
        for (int j = 0; j < 4; ++j) acc[i][j] = (f32x4){0.f, 0.f, 0.f, 0.f};

    for (int k0 = 0; k0 < K; k0 += BK) {
        __syncthreads();
        stage_tile(Ab, lda, k0, sA, tid);
        stage_tile(Bb, ldb, k0, sB, tid);
        __syncthreads();
#pragma unroll
        for (int kh = 0; kh < 2; ++kh) {
            bf16x8 af[4], bfr[4];
#pragma unroll
            for (int mi = 0; mi < 4; ++mi)
                af[mi] = ldfrag(sA, wm + mi * 16 + l16, kh * 4 + quad);
#pragma unroll
            for (int nj = 0; nj < 4; ++nj)
                bfr[nj] = ldfrag(sB, wn + nj * 16 + l16, kh * 4 + quad);
#pragma unroll
            for (int mi = 0; mi < 4; ++mi)
#pragma unroll
                for (int nj = 0; nj < 4; ++nj)
                    acc[mi][nj] = __builtin_amdgcn_mfma_f32_16x16x32_bf16(af[mi], bfr[nj], acc[mi][nj], 0, 0, 0);
        }
    }

#pragma unroll
    for (int mi = 0; mi < 4; ++mi) {
        int row = m0 + wm + mi * 16 + quad * 4;
#pragma unroll
        for (int nj = 0; nj < 4; ++nj) {
            int col = n0 + wn + nj * 16 + l16;
#pragma unroll
            for (int r = 0; r < 4; ++r)
                C[(long long)(row + r) * ldc + col] = f2b(acc[mi][nj][r] * scale);
        }
    }
}

// ---------- fused gate_up GEMM + SiLU: h = silu(x@Wg^T) * (x@Wu^T) ----------
__global__ __launch_bounds__(256)
void k_gemm_silu(const ushort_t* __restrict__ A, const ushort_t* __restrict__ Bg,
                 const ushort_t* __restrict__ Bu, ushort_t* __restrict__ H,
                 int K, int lda, int ldb, int ldh) {
    __shared__ __attribute__((aligned(16))) ushort_t sA[BM * BK];
    __shared__ __attribute__((aligned(16))) ushort_t sBg[BN * BK];
    __shared__ __attribute__((aligned(16))) ushort_t sBu[BN * BK];

    int m0, n0;
    tile_decode(m0, n0);
    const ushort_t* Ab = A + (long long)m0 * lda;
    const ushort_t* Bgb = Bg + (long long)n0 * ldb;
    const ushort_t* Bub = Bu + (long long)n0 * ldb;

    const int tid = threadIdx.x;
    const int lane = tid & 63, quad = lane >> 4, l16 = lane & 15;
    const int wave = tid >> 6;
    const int wm = (wave >> 1) * 64, wn = (wave & 1) * 64;

    f32x4 ag[4][4], au[4][4];
#pragma unroll
    for (int i = 0; i < 4; ++i)
#pragma unroll
        for (int j = 0; j < 4; ++j) { ag[i][j] = (f32x4){0,0,0,0}; au[i][j] = (f32x4){0,0,0,0}; }

    for (int k0 = 0; k0 < K; k0 += BK) {
        __syncthreads();
        stage_tile(Ab, lda, k0, sA, tid);
        stage_tile(Bgb, ldb, k0, sBg, tid);
        stage_tile(Bub, ldb, k0, sBu, tid);
        __syncthreads();
#pragma unroll
        for (int kh = 0; kh < 2; ++kh) {
            bf16x8 af[4], bg[4], bu[4];
#pragma unroll
            for (int mi = 0; mi < 4; ++mi)
                af[mi] = ldfrag(sA, wm + mi * 16 + l16, kh * 4 + quad);
#pragma unroll
            for (int nj = 0; nj < 4; ++nj) {
                bg[nj] = ldfrag(sBg, wn + nj * 16 + l16, kh * 4 + quad);
                bu[nj] = ldfrag(sBu, wn + nj * 16 + l16, kh * 4 + quad);
            }
#pragma unroll
            for (int mi = 0; mi < 4; ++mi)
#pragma unroll
                for (int nj = 0; nj < 4; ++nj) {
                    ag[mi][nj] = __builtin_amdgcn_mfma_f32_16x16x32_bf16(af[mi], bg[nj], ag[mi][nj], 0, 0, 0);
                    au[mi][nj] = __builtin_amdgcn_mfma_f32_16x16x32_bf16(af[mi], bu[nj], au[mi][nj], 0, 0, 0);
                }
        }
    }

#pragma unroll
    for (int mi = 0; mi < 4; ++mi) {
        int row = m0 + wm + mi * 16 + quad * 4;
#pragma unroll
        for (int nj = 0; nj < 4; ++nj) {
            int col = n0 + wn + nj * 16 + l16;
#pragma unroll
            for (int r = 0; r < 4; ++r) {
                float g = ag[mi][nj][r], u = au[mi][nj][r];
                float s = g / (1.f + __expf(-g));
                H[(long long)(row + r) * ldh + col] = f2b(s * u);
            }
        }
    }
}

// ---------- triangular P GEMM: P[b, i*256+m, j*256+n] = sum_f h_i[m,f] h_j[n,f], j<i ----------
__global__ __launch_bounds__(256)
void k_gemm_tri(const ushort_t* __restrict__ H, ushort_t* __restrict__ P,
                int K, int ldh, int ldp, long long sHb, long long sPb, int npairs) {
    __shared__ __attribute__((aligned(16))) ushort_t sA[BM * BK];
    __shared__ __attribute__((aligned(16))) ushort_t sB[BN * BK];

    const int z = blockIdx.z, bb = z / npairs;
    int p = z % npairs;
    int i = 1, rem = p;
    while (rem >= i) { rem -= i; ++i; }
    const int j = rem;

    const int m0 = blockIdx.y * BM;
    const int n0 = blockIdx.x * BN;
    const ushort_t* Ab = H + bb * sHb + (long long)(i * 256 + m0) * ldh;
    const ushort_t* Bb = H + bb * sHb + (long long)(j * 256 + n0) * ldh;

    const int tid = threadIdx.x;
    const int lane = tid & 63, quad = lane >> 4, l16 = lane & 15;
    const int wave = tid >> 6;
    const int wm = (wave >> 1) * 64, wn = (wave & 1) * 64;

    f32x4 acc[4][4];
#pragma unroll
    for (int a = 0; a < 4; ++a)
#pragma unroll
        for (int c = 0; c < 4; ++c) acc[a][c] = (f32x4){0,0,0,0};

    for (int k0 = 0; k0 < K; k0 += BK) {
        __syncthreads();
        stage_tile(Ab, ldh, k0, sA, tid);
        stage_tile(Bb, ldh, k0, sB, tid);
        __syncthreads();
#pragma unroll
        for (int kh = 0; kh < 2; ++kh) {
            bf16x8 af[4], bfr[4];
#pragma unroll
            for (int mi = 0; mi < 4; ++mi)
                af[mi] = ldfrag(sA, wm + mi * 16 + l16, kh * 4 + quad);
#pragma unroll
            for (int nj = 0; nj < 4; ++nj)
                bfr[nj] = ldfrag(sB, wn + nj * 16 + l16, kh * 4 + quad);
#pragma unroll
            for (int mi = 0; mi < 4; ++mi)
#pragma unroll
                for (int nj = 0; nj < 4; ++nj)
                    acc[mi][nj] = __builtin_amdgcn_mfma_f32_16x16x32_bf16(af[mi], bfr[nj], acc[mi][nj], 0, 0, 0);
        }
    }

    ushort_t* Pp = P + bb * sPb;
#pragma unroll
    for (int mi = 0; mi < 4; ++mi) {
        int row = i * 256 + m0 + wm + mi * 16 + quad * 4;
#pragma unroll
        for (int nj = 0; nj < 4; ++nj) {
            int col = j * 256 + n0 + wn + nj * 16 + l16;
#pragma unroll
            for (int r = 0; r < 4; ++r)
                Pp[(long long)(row + r) * ldp + col] = f2b(acc[mi][nj][r]);
        }
    }
}

// ---------- fused output GEMM: out[b,i] = [h_i | P_i,0:i*C] @ [wdown | LR*tpT]^T ----------
// K = 4096 + i*256; all operand lds are 4096. LR pre-folded into tpT. fp32 store.
__global__ __launch_bounds__(256)
void k_gemm_out(const ushort_t* __restrict__ h, const ushort_t* __restrict__ wdown,
                const ushort_t* __restrict__ P, const ushort_t* __restrict__ tpT,
                float* __restrict__ out) {
    constexpr int T = 4096, D = 1024, F = 4096, C = 256, K1 = 4096;
    __shared__ __attribute__((aligned(16))) ushort_t sA[BM * BK];
    __shared__ __attribute__((aligned(16))) ushort_t sB[BN * BK];

    const int z = blockIdx.z, bb = z >> 4, ii = z & 15;
    const int K2 = ii * C;
    int m0, n0;
    tile_decode(m0, n0);

    const ushort_t* A1 = h + (long long)bb * T * F + (long long)(ii * C + m0) * F;       // ld F=4096
    const ushort_t* B1 = wdown + (long long)n0 * F;                                       // ld 4096
    const ushort_t* A2 = P + (long long)bb * T * T + (long long)(ii * C + m0) * T;        // ld T=4096
    const ushort_t* B2 = tpT + (long long)bb * D * T + (long long)n0 * T;                 // ld 4096

    const int tid = threadIdx.x;
    const int lane = tid & 63, quad = lane >> 4, l16 = lane & 15;
    const int wave = tid >> 6;
    const int wm = (wave >> 1) * 64, wn = (wave & 1) * 64;

    f32x4 acc[4][4];
#pragma unroll
    for (int i = 0; i < 4; ++i)
#pragma unroll
        for (int j = 0; j < 4; ++j) acc[i][j] = (f32x4){0.f, 0.f, 0.f, 0.f};

    const int K = K1 + K2;
    for (int k0 = 0; k0 < K; k0 += BK) {
        const ushort_t* As = (k0 < K1) ? A1 + k0 : A2 + (k0 - K1);
        const ushort_t* Bs = (k0 < K1) ? B1 + k0 : B2 + (k0 - K1);
        __syncthreads();
        stage_tile(As, 4096, 0, sA, tid);
        stage_tile(Bs, 4096, 0, sB, tid);
        __syncthreads();
#pragma unroll
        for (int kh = 0; kh < 2; ++kh) {
            bf16x8 af[4], bfr[4];
#pragma unroll
            for (int mi = 0; mi < 4; ++mi)
                af[mi] = ldfrag(sA, wm + mi * 16 + l16, kh * 4 + quad);
#pragma unroll
            for (int nj = 0; nj < 4; ++nj)
                bfr[nj] = ldfrag(sB, wn + nj * 16 + l16, kh * 4 + quad);
#pragma unroll
            for (int mi = 0; mi < 4; ++mi)
#pragma unroll
                for (int nj = 0; nj < 4; ++nj)
                    acc[mi][nj] = __builtin_amdgcn_mfma_f32_16x16x32_bf16(af[mi], bfr[nj], acc[mi][nj], 0, 0, 0);
        }
    }

    float* Op = out + (long long)bb * T * D + (long long)ii * C * D;
#pragma unroll
    for (int mi = 0; mi < 4; ++mi) {
        int row = m0 + wm + mi * 16 + quad * 4;
#pragma unroll
        for (int nj = 0; nj < 4; ++nj) {
            int col = n0 + wn + nj * 16 + l16;
#pragma unroll
            for (int r = 0; r < 4; ++r)
                Op[(long long)(row + r) * D + col] = acc[mi][nj][r];
        }
    }
}

// ---------- launch ----------
extern "C" void kernel_launch(void* const* d_in, const int* in_sizes, int n_in,
                              void* d_out, int out_size, void* d_ws, size_t ws_size,
                              hipStream_t stream) {
    const float* x         = (const float*)d_in[0];
    const float* ttt_tgt   = (const float*)d_in[1];
    const float* w_gate_up = (const float*)d_in[2];
    const float* w_down    = (const float*)d_in[3];
    const float* ttt_proj  = (const float*)d_in[4];
    const float* conv_w    = (const float*)d_in[5];
    const float* conv_b    = (const float*)d_in[6];
    float* out = (float*)d_out;
    (void)in_sizes; (void)n_in; (void)out_size; (void)ws_size;

    constexpr int Bb = 2, T = 4096, D = 1024, F = 4096, C = 256;
    constexpr float LR = 0.01f;

    // workspace (161.5 MB):
    //   [0,64M): x_bf|wgu_bf|t_bf|tproj  -> later aliased by P (B,T,T) bf16
    //   [64M..): proj_bf 2M | wdown_bf 8M | tpT 16M | h 64M
    char* ws = (char*)d_ws;
    ushort_t* x_bf     = (ushort_t*)(ws);
    ushort_t* wgu_bf   = (ushort_t*)(ws + 16777216LL);
    ushort_t* t_bf     = (ushort_t*)(ws + 2 * 16777216LL);
    ushort_t* tproj    = (ushort_t*)(ws + 3 * 16777216LL);
    ushort_t* P        = (ushort_t*)(ws);
    ushort_t* proj_bf  = (ushort_t*)(ws + 67108864LL);
    ushort_t* wdown_bf = (ushort_t*)(ws + 67108864LL + 2097152LL);
    ushort_t* tpT      = (ushort_t*)(ws + 67108864LL + 2097152LL + 8388608LL);
    ushort_t* h        = (ushort_t*)(ws + 67108864LL + 2097152LL + 8388608LL + 16777216LL);

    // 1) converts
    k_cvt<<<(Bb * T * D) / 256, 256, 0, stream>>>(x, x_bf, Bb * T * D);
    k_cvt<<<(2 * F * D) / 256, 256, 0, stream>>>(w_gate_up, wgu_bf, 2 * F * D);
    k_cvt<<<(D * D) / 256, 256, 0, stream>>>(ttt_proj, proj_bf, D * D);
    k_cvt<<<(D * F) / 256, 256, 0, stream>>>(w_down, wdown_bf, D * F);

    // 2) causal depthwise conv -> t_bf (B,T,D) bf16
    k_conv<<<(Bb * T * D) / 256, 256, 0, stream>>>(ttt_tgt, conv_w, conv_b, t_bf, T, D, Bb * T * D);

    // 3) tproj = LR * (t @ ttt_proj^T) : M=B*T, N=D, K=D -> bf16  (LR folded here)
    k_gemm_nt<<<dim3(D / BN, (Bb * T) / BM, 1), 256, 0, stream>>>(
        t_bf, proj_bf, tproj, D, D, D, D, LR);

    // 4) transpose per batch: tproj (B,T,D) -> tpT (B,D,T)
    k_transpose<<<dim3(D / 32, T / 32, Bb), 256, 0, stream>>>(tproj, tpT, T, D);

    // 5) h = silu(x@Wg^T)*(x@Wu^T) : M=B*T, N=F, K=D
    k_gemm_silu<<<dim3(F / BN, (Bb * T) / BM, 1), 256, 0, stream>>>(
        x_bf, wgu_bf, wgu_bf + (long long)F * D, h, D, D, D, F);

    // 6) P lower chunk-blocks: P[b, i*C.., j*C..] = h_i h_j^T, j<i
    k_gemm_tri<<<dim3(C / BN, C / BM, Bb * 120), 256, 0, stream>>>(
        h, P, F, F, T, (long long)T * F, (long long)T * T, 120);

    // 7) out[b,i] = [h_i | P] @ [wdown | LR*tpT]^T  (variable K = 4096 + i*256)
    k_gemm_out<<<dim3(D / BN, C / BM, Bb * 16), 256, 0, stream>>>(
        h, wdown_bf, P, tpT, out);
}

// Round 5
// 732.997 us; speedup vs baseline: 1.3306x; 1.0687x over previous
//
#include <hip/hip_runtime.h>
#include <hip/hip_bf16.h>
#include <stdint.h>

typedef unsigned short ushort_t;
typedef __bf16 bf16x8 __attribute__((ext_vector_type(8)));
typedef float f32x4 __attribute__((ext_vector_type(4)));

#define BM 128
#define BN 128
#define BK 64   // 16 KB per tile; XOR-swizzled 16B chunks (bank-conflict-free, verified R3)

// ---------- helpers ----------
__device__ inline float b2f(ushort_t u) {
    unsigned int x = ((unsigned int)u) << 16;
    float f; __builtin_memcpy(&f, &x, 4); return f;
}
__device__ inline ushort_t f2b(float f) {
    unsigned int x; __builtin_memcpy(&x, &f, 4);
    unsigned int r = (x + 0x7FFFu + ((x >> 16) & 1u)) >> 16;
    return (ushort_t)r;
}
__device__ inline void stage16(const ushort_t* g, ushort_t* s) {
    __builtin_amdgcn_global_load_lds((const __attribute__((address_space(1))) void*)g,
                                     (__attribute__((address_space(3))) void*)s, 16, 0, 0);
}
// stage one 128x64 bf16 tile; LDS chunk e holds global chunk ((e&7)^(row&7)) of row e>>3
__device__ inline void stage_tile(const ushort_t* G, int ld, int k0, ushort_t* S, int tid) {
#pragma unroll
    for (int t = 0; t < 4; ++t) {
        int e = tid + t * 256;
        int row = e >> 3;
        int sw = ((e & 7) ^ (row & 7)) * 8;
        stage16(G + (long long)row * ld + k0 + sw, &S[e * 8]);
    }
}
__device__ inline bf16x8 ldfrag(const ushort_t* S, int r, int c) {
    return *(const bf16x8*)&S[r * BK + ((c ^ (r & 7)) * 8)];
}
// XCD-aware tile decode (verified R4: FETCH 532->130 MB): XCD = lin%8; XCD k owns a
// fixed set of nx/8 n-tiles (B stays L2-resident), sweeps m, cycling owned n-tiles.
__device__ inline void tile_decode(int& m0, int& n0) {
    const int nx = gridDim.x;
    int lin = blockIdx.y * nx + blockIdx.x;
    if ((nx & 7) == 0) {
        int q = nx >> 3;
        int k = lin & 7, s = lin >> 3;
        n0 = (k * q + s % q) * BN;
        m0 = (s / q) * BM;
    } else {
        m0 = blockIdx.y * BM;
        n0 = blockIdx.x * BN;
    }
}

// ---------- fused fp32->bf16 convert for x | wgu | proj | wdown (float4-wide) ----------
__global__ void k_cvt4(const float* __restrict__ x, const float* __restrict__ wgu,
                       const float* __restrict__ proj, const float* __restrict__ wdown,
                       ushort_t* __restrict__ xb, ushort_t* __restrict__ gb,
                       ushort_t* __restrict__ pb, ushort_t* __restrict__ wb) {
    // 4-elem units: x 2097152 | wgu 2097152 | proj 262144 | wdown 1048576 = 5505024 total
    int i = blockIdx.x * 256 + threadIdx.x;
    const float* src; ushort_t* dst; int off;
    if (i < 2097152)      { src = x;     dst = xb; off = i; }
    else if (i < 4194304) { src = wgu;   dst = gb; off = i - 2097152; }
    else if (i < 4456448) { src = proj;  dst = pb; off = i - 4194304; }
    else                  { src = wdown; dst = wb; off = i - 4456448; }
    float4 v = ((const float4*)src)[off];
    ushort4 o; o.x = f2b(v.x); o.y = f2b(v.y); o.z = f2b(v.z); o.w = f2b(v.w);
    ((ushort4*)dst)[off] = o;
}

// ---------- causal depthwise conv (K=5), fp32 in, bf16 out ----------
__global__ void k_conv(const float* __restrict__ x, const float* __restrict__ w,
                       const float* __restrict__ bias, ushort_t* __restrict__ out,
                       int T, int D, int n) {
    int idx = blockIdx.x * blockDim.x + threadIdx.x;
    if (idx >= n) return;
    int d = idx % D;
    int t = (idx / D) % T;
    int b = idx / (D * T);
    float acc = bias[d];
#pragma unroll
    for (int k = 0; k < 5; ++k) {
        int ts = t - 4 + k;
        if (ts >= 0) acc += x[(long long)b * T * D + (long long)ts * D + d] * w[d * 5 + k];
    }
    out[idx] = f2b(acc);
}

// ---------- batched bf16 NT GEMM (bf16 out): C[m,n] = scale * sum_k A[m,k]*B[n,k] ----------
__global__ __launch_bounds__(256, 4)
void k_gemm_nt(const ushort_t* __restrict__ A, const ushort_t* __restrict__ B,
               ushort_t* __restrict__ C, int K, int lda, int ldb, int ldc,
               long long sAb, long long sBb, long long sCb, float scale) {
    __shared__ __attribute__((aligned(16))) ushort_t sA[BM * BK];
    __shared__ __attribute__((aligned(16))) ushort_t sB[BN * BK];

    int m0, n0;
    tile_decode(m0, n0);
    const int bb = blockIdx.z;
    const ushort_t* Ab = A + bb * sAb + (long long)m0 * lda;
    const ushort_t* Bb = B + bb * sBb + (long long)n0 * ldb;

    const int tid = threadIdx.x;
    const int lane = tid & 63, quad = lane >> 4, l16 = lane & 15;
    const int wave = tid >> 6;
    const int wm = (wave >> 1) * 64, wn = (wave & 1) * 64;

    f32x4 acc[4][4];
#pragma unroll
    for (int i = 0; i < 4; ++i)
#pragma unroll
        for (int j = 0; j < 4; ++j) acc[i][j] = (f32x4){0.f, 0.f, 0.f, 0.f};

    for (int k0 = 0; k0 < K; k0 += BK) {
        __syncthreads();
        stage_tile(Ab, lda, k0, sA, tid);
        stage_tile(Bb, ldb, k0, sB, tid);
        __syncthreads();
#pragma unroll
        for (int kh = 0; kh < 2; ++kh) {
            bf16x8 af[4], bfr[4];
#pragma unroll
            for (int mi = 0; mi < 4; ++mi)
                af[mi] = ldfrag(sA, wm + mi * 16 + l16, kh * 4 + quad);
#pragma unroll
            for (int nj = 0; nj < 4; ++nj)
                bfr[nj] = ldfrag(sB, wn + nj * 16 + l16, kh * 4 + quad);
#pragma unroll
            for (int mi = 0; mi < 4; ++mi)
#pragma unroll
                for (int nj = 0; nj < 4; ++nj)
                    acc[mi][nj] = __builtin_amdgcn_mfma_f32_16x16x32_bf16(af[mi], bfr[nj], acc[mi][nj], 0, 0, 0);
        }
    }

    ushort_t* Cp = C + bb * sCb;
#pragma unroll
    for (int mi = 0; mi < 4; ++mi) {
        int row = m0 + wm + mi * 16 + quad * 4;
#pragma unroll
        for (int nj = 0; nj < 4; ++nj) {
            int col = n0 + wn + nj * 16 + l16;
#pragma unroll
            for (int r = 0; r < 4; ++r)
                Cp[(long long)(row + r) * ldc + col] = f2b(acc[mi][nj][r] * scale);
        }
    }
}

// ---------- fused gate_up GEMM + SiLU: h = silu(x@Wg^T) * (x@Wu^T) ----------
__global__ __launch_bounds__(256)
void k_gemm_silu(const ushort_t* __restrict__ A, const ushort_t* __restrict__ Bg,
                 const ushort_t* __restrict__ Bu, ushort_t* __restrict__ H,
                 int K, int lda, int ldb, int ldh) {
    __shared__ __attribute__((aligned(16))) ushort_t sA[BM * BK];
    __shared__ __attribute__((aligned(16))) ushort_t sBg[BN * BK];
    __shared__ __attribute__((aligned(16))) ushort_t sBu[BN * BK];

    int m0, n0;
    tile_decode(m0, n0);
    const ushort_t* Ab = A + (long long)m0 * lda;
    const ushort_t* Bgb = Bg + (long long)n0 * ldb;
    const ushort_t* Bub = Bu + (long long)n0 * ldb;

    const int tid = threadIdx.x;
    const int lane = tid & 63, quad = lane >> 4, l16 = lane & 15;
    const int wave = tid >> 6;
    const int wm = (wave >> 1) * 64, wn = (wave & 1) * 64;

    f32x4 ag[4][4], au[4][4];
#pragma unroll
    for (int i = 0; i < 4; ++i)
#pragma unroll
        for (int j = 0; j < 4; ++j) { ag[i][j] = (f32x4){0,0,0,0}; au[i][j] = (f32x4){0,0,0,0}; }

    for (int k0 = 0; k0 < K; k0 += BK) {
        __syncthreads();
        stage_tile(Ab, lda, k0, sA, tid);
        stage_tile(Bgb, ldb, k0, sBg, tid);
        stage_tile(Bub, ldb, k0, sBu, tid);
        __syncthreads();
#pragma unroll
        for (int kh = 0; kh < 2; ++kh) {
            bf16x8 af[4], bg[4], bu[4];
#pragma unroll
            for (int mi = 0; mi < 4; ++mi)
                af[mi] = ldfrag(sA, wm + mi * 16 + l16, kh * 4 + quad);
#pragma unroll
            for (int nj = 0; nj < 4; ++nj) {
                bg[nj] = ldfrag(sBg, wn + nj * 16 + l16, kh * 4 + quad);
                bu[nj] = ldfrag(sBu, wn + nj * 16 + l16, kh * 4 + quad);
            }
#pragma unroll
            for (int mi = 0; mi < 4; ++mi)
#pragma unroll
                for (int nj = 0; nj < 4; ++nj) {
                    ag[mi][nj] = __builtin_amdgcn_mfma_f32_16x16x32_bf16(af[mi], bg[nj], ag[mi][nj], 0, 0, 0);
                    au[mi][nj] = __builtin_amdgcn_mfma_f32_16x16x32_bf16(af[mi], bu[nj], au[mi][nj], 0, 0, 0);
                }
        }
    }

#pragma unroll
    for (int mi = 0; mi < 4; ++mi) {
        int row = m0 + wm + mi * 16 + quad * 4;
#pragma unroll
        for (int nj = 0; nj < 4; ++nj) {
            int col = n0 + wn + nj * 16 + l16;
#pragma unroll
            for (int r = 0; r < 4; ++r) {
                float g = ag[mi][nj][r], u = au[mi][nj][r];
                float s = g / (1.f + __expf(-g));
                H[(long long)(row + r) * ldh + col] = f2b(s * u);
            }
        }
    }
}

// ---------- triangular P GEMM: P[b, i*256+m, j*256+n] = sum_f h_i[m,f] h_j[n,f], j<i ----------
__global__ __launch_bounds__(256, 4)
void k_gemm_tri(const ushort_t* __restrict__ H, ushort_t* __restrict__ P,
                int K, int ldh, int ldp, long long sHb, long long sPb, int npairs) {
    __shared__ __attribute__((aligned(16))) ushort_t sA[BM * BK];
    __shared__ __attribute__((aligned(16))) ushort_t sB[BN * BK];

    const int z = blockIdx.z, bb = z / npairs;
    int p = z % npairs;
    int i = 1, rem = p;
    while (rem >= i) { rem -= i; ++i; }
    const int j = rem;

    const int m0 = blockIdx.y * BM;
    const int n0 = blockIdx.x * BN;
    const ushort_t* Ab = H + bb * sHb + (long long)(i * 256 + m0) * ldh;
    const ushort_t* Bb = H + bb * sHb + (long long)(j * 256 + n0) * ldh;

    const int tid = threadIdx.x;
    const int lane = tid & 63, quad = lane >> 4, l16 = lane & 15;
    const int wave = tid >> 6;
    const int wm = (wave >> 1) * 64, wn = (wave & 1) * 64;

    f32x4 acc[4][4];
#pragma unroll
    for (int a = 0; a < 4; ++a)
#pragma unroll
        for (int c = 0; c < 4; ++c) acc[a][c] = (f32x4){0,0,0,0};

    for (int k0 = 0; k0 < K; k0 += BK) {
        __syncthreads();
        stage_tile(Ab, ldh, k0, sA, tid);
        stage_tile(Bb, ldh, k0, sB, tid);
        __syncthreads();
#pragma unroll
        for (int kh = 0; kh < 2; ++kh) {
            bf16x8 af[4], bfr[4];
#pragma unroll
            for (int mi = 0; mi < 4; ++mi)
                af[mi] = ldfrag(sA, wm + mi * 16 + l16, kh * 4 + quad);
#pragma unroll
            for (int nj = 0; nj < 4; ++nj)
                bfr[nj] = ldfrag(sB, wn + nj * 16 + l16, kh * 4 + quad);
#pragma unroll
            for (int mi = 0; mi < 4; ++mi)
#pragma unroll
                for (int nj = 0; nj < 4; ++nj)
                    acc[mi][nj] = __builtin_amdgcn_mfma_f32_16x16x32_bf16(af[mi], bfr[nj], acc[mi][nj], 0, 0, 0);
        }
    }

    ushort_t* Pp = P + bb * sPb;
#pragma unroll
    for (int mi = 0; mi < 4; ++mi) {
        int row = i * 256 + m0 + wm + mi * 16 + quad * 4;
#pragma unroll
        for (int nj = 0; nj < 4; ++nj) {
            int col = j * 256 + n0 + wn + nj * 16 + l16;
#pragma unroll
            for (int r = 0; r < 4; ++r)
                Pp[(long long)(row + r) * ldp + col] = f2b(acc[mi][nj][r]);
        }
    }
}

// ---------- fused output GEMM: out[b,i] = [h_i | P_i,0:i*C] @ [wdown | tpT]^T ----------
// K = 4096 + i*256; all operand lds are 4096. LR pre-folded into tpT. fp32 store.
__global__ __launch_bounds__(256, 4)
void k_gemm_out(const ushort_t* __restrict__ h, const ushort_t* __restrict__ wdown,
                const ushort_t* __restrict__ P, const ushort_t* __restrict__ tpT,
                float* __restrict__ out) {
    constexpr int T = 4096, D = 1024, F = 4096, C = 256, K1 = 4096;
    __shared__ __attribute__((aligned(16))) ushort_t sA[BM * BK];
    __shared__ __attribute__((aligned(16))) ushort_t sB[BN * BK];

    const int z = blockIdx.z, bb = z >> 4, ii = z & 15;
    const int K2 = ii * C;
    int m0, n0;
    tile_decode(m0, n0);

    const ushort_t* A1 = h + (long long)bb * T * F + (long long)(ii * C + m0) * F;
    const ushort_t* B1 = wdown + (long long)n0 * F;
    const ushort_t* A2 = P + (long long)bb * T * T + (long long)(ii * C + m0) * T;
    const ushort_t* B2 = tpT + (long long)bb * D * T + (long long)n0 * T;

    const int tid = threadIdx.x;
    const int lane = tid & 63, quad = lane >> 4, l16 = lane & 15;
    const int wave = tid >> 6;
    const int wm = (wave >> 1) * 64, wn = (wave & 1) * 64;

    f32x4 acc[4][4];
#pragma unroll
    for (int i = 0; i < 4; ++i)
#pragma unroll
        for (int j = 0; j < 4; ++j) acc[i][j] = (f32x4){0.f, 0.f, 0.f, 0.f};

    const int K = K1 + K2;
    for (int k0 = 0; k0 < K; k0 += BK) {
        const ushort_t* As = (k0 < K1) ? A1 + k0 : A2 + (k0 - K1);
        const ushort_t* Bs = (k0 < K1) ? B1 + k0 : B2 + (k0 - K1);
        __syncthreads();
        stage_tile(As, 4096, 0, sA, tid);
        stage_tile(Bs, 4096, 0, sB, tid);
        __syncthreads();
#pragma unroll
        for (int kh = 0; kh < 2; ++kh) {
            bf16x8 af[4], bfr[4];
#pragma unroll
            for (int mi = 0; mi < 4; ++mi)
                af[mi] = ldfrag(sA, wm + mi * 16 + l16, kh * 4 + quad);
#pragma unroll
            for (int nj = 0; nj < 4; ++nj)
                bfr[nj] = ldfrag(sB, wn + nj * 16 + l16, kh * 4 + quad);
#pragma unroll
            for (int mi = 0; mi < 4; ++mi)
#pragma unroll
                for (int nj = 0; nj < 4; ++nj)
                    acc[mi][nj] = __builtin_amdgcn_mfma_f32_16x16x32_bf16(af[mi], bfr[nj], acc[mi][nj], 0, 0, 0);
        }
    }

    float* Op = out + (long long)bb * T * D + (long long)ii * C * D;
#pragma unroll
    for (int mi = 0; mi < 4; ++mi) {
        int row = m0 + wm + mi * 16 + quad * 4;
#pragma unroll
        for (int nj = 0; nj < 4; ++nj) {
            int col = n0 + wn + nj * 16 + l16;
#pragma unroll
            for (int r = 0; r < 4; ++r)
                Op[(long long)(row + r) * D + col] = acc[mi][nj][r];
        }
    }
}

// ---------- launch ----------
extern "C" void kernel_launch(void* const* d_in, const int* in_sizes, int n_in,
                              void* d_out, int out_size, void* d_ws, size_t ws_size,
                              hipStream_t stream) {
    const float* x         = (const float*)d_in[0];
    const float* ttt_tgt   = (const float*)d_in[1];
    const float* w_gate_up = (const float*)d_in[2];
    const float* w_down    = (const float*)d_in[3];
    const float* ttt_proj  = (const float*)d_in[4];
    const float* conv_w    = (const float*)d_in[5];
    const float* conv_b    = (const float*)d_in[6];
    float* out = (float*)d_out;
    (void)in_sizes; (void)n_in; (void)out_size; (void)ws_size;

    constexpr int Bb = 2, T = 4096, D = 1024, F = 4096, C = 256;
    constexpr float LR = 0.01f;

    // workspace (154 MB):
    //   [0,64M): x_bf(16M) | wgu_bf(16M) | t_bf(16M) | scratch  -> later aliased by P (B,T,T) bf16
    //   [64M..): proj_bf 2M | wdown_bf 8M | tpT 16M | h 64M
    char* ws = (char*)d_ws;
    ushort_t* x_bf     = (ushort_t*)(ws);
    ushort_t* wgu_bf   = (ushort_t*)(ws + 16777216LL);
    ushort_t* t_bf     = (ushort_t*)(ws + 2 * 16777216LL);
    ushort_t* P        = (ushort_t*)(ws);
    ushort_t* proj_bf  = (ushort_t*)(ws + 67108864LL);
    ushort_t* wdown_bf = (ushort_t*)(ws + 67108864LL + 2097152LL);
    ushort_t* tpT      = (ushort_t*)(ws + 67108864LL + 2097152LL + 8388608LL);
    ushort_t* h        = (ushort_t*)(ws + 67108864LL + 2097152LL + 8388608LL + 16777216LL);

    // 1) fused converts (x | wgu | proj | wdown), float4-wide
    k_cvt4<<<21504, 256, 0, stream>>>(x, w_gate_up, ttt_proj, w_down,
                                      x_bf, wgu_bf, proj_bf, wdown_bf);

    // 2) causal depthwise conv -> t_bf (B,T,D) bf16
    k_conv<<<(Bb * T * D) / 256, 256, 0, stream>>>(ttt_tgt, conv_w, conv_b, t_bf, T, D, Bb * T * D);

    // 3) tpT[b] = LR * (proj @ t[b]^T) : M=D, N=T, K=D -> bf16 (B,D,T); kills transpose
    k_gemm_nt<<<dim3(T / BN, D / BM, Bb), 256, 0, stream>>>(
        proj_bf, t_bf, tpT, D, D, D, T,
        0, (long long)T * D, (long long)D * T, LR);

    // 4) h = silu(x@Wg^T)*(x@Wu^T) : M=B*T, N=F, K=D
    k_gemm_silu<<<dim3(F / BN, (Bb * T) / BM, 1), 256, 0, stream>>>(
        x_bf, wgu_bf, wgu_bf + (long long)F * D, h, D, D, D, F);

    // 5) P lower chunk-blocks: P[b, i*C.., j*C..] = h_i h_j^T, j<i
    k_gemm_tri<<<dim3(C / BN, C / BM, Bb * 120), 256, 0, stream>>>(
        h, P, F, F, T, (long long)T * F, (long long)T * T, 120);

    // 6) out[b,i] = [h_i | P] @ [wdown | LR*tpT]^T  (variable K = 4096 + i*256)
    k_gemm_out<<<dim3(D / BN, C / BM, Bb * 16), 256, 0, stream>>>(
        h, wdown_bf, P, tpT, out);
}